// Round 5
// baseline (135.428 us; speedup 1.0000x reference)
//
#include <hip/hip_runtime.h>
#include <hip/hip_bf16.h>
#include <stdint.h>

using bf16   = __bf16;
using bf16x4 = __attribute__((ext_vector_type(4))) __bf16;
using bf16x8 = __attribute__((ext_vector_type(8))) __bf16;
using f32x4  = __attribute__((ext_vector_type(4))) float;

// geometry (fixed by the problem)
static constexpr int BATCH = 4, SEQ = 2048, DIM = 512, HEADS = 8, DK = 64;
static constexpr int M    = BATCH * SEQ;   // 8192 rows of x
static constexpr int NQKV = 3 * DIM;       // 1536

#define GLD16(src, dst)                                                        \
    __builtin_amdgcn_global_load_lds(                                          \
        (const __attribute__((address_space(1))) void*)(src),                  \
        (__attribute__((address_space(3))) void*)(dst), 16, 0, 0)

#define WAITVM(N)  asm volatile("s_waitcnt vmcnt(" #N ")" ::: "memory")
#define WAITLGKM0  asm volatile("s_waitcnt lgkmcnt(0)" ::: "memory")

// ---------------------------------------------------------------------------
// Kernel 1: x -> bf16; W [512][1536] fp32 -> Wt [1536][512] bf16; zero S.
// ---------------------------------------------------------------------------
__global__ __launch_bounds__(256) void k_prep(const float* __restrict__ x,
                                              const float* __restrict__ w,
                                              bf16* __restrict__ xbf,
                                              bf16* __restrict__ wt,
                                              float* __restrict__ S)
{
    const int bid = blockIdx.x;
    const int t   = threadIdx.x;
    const int XB  = (M * DIM) / (256 * 4);                 // 4096 blocks
    const int WB  = (DIM / 32) * (NQKV / 32);              // 768 blocks

    if (bid < XB) {
        const int i = (bid * 256 + t) * 4;
        float4 v = *(const float4*)(x + i);
        bf16x4 o = { (bf16)v.x, (bf16)v.y, (bf16)v.z, (bf16)v.w };
        *(bf16x4*)(xbf + i) = o;
    } else if (bid < XB + WB) {
        const int wb = bid - XB;
        const int rt = wb / 48, ct = wb - rt * 48;          // k-tile, n-tile
        __shared__ float tile[32][33];
        const int r = t >> 5, c = t & 31;
        #pragma unroll
        for (int i = 0; i < 4; ++i)
            tile[r + i * 8][c] = w[(rt * 32 + r + i * 8) * NQKV + ct * 32 + c];
        __syncthreads();
        #pragma unroll
        for (int i = 0; i < 4; ++i)
            wt[(ct * 32 + r + i * 8) * DIM + rt * 32 + c] = (bf16)tile[c][r + i * 8];
    } else {
        const int sb = bid - XB - WB;                       // 128 blocks
        const int i  = (sb * 256 + t) * 4;
        *(f32x4*)(S + i) = (f32x4){0.f, 0.f, 0.f, 0.f};
    }
}

// ---------------------------------------------------------------------------
// Kernel 2 (mega): per (m-tile 128, head h): GEMM cols {q_h|k_h|v_h}
// (128x192, 6 waves of 64x64).  BK=32, 16 K-steps, 3 LDS buffers, 2-deep
// prefetch with COUNTED vmcnt: stage t+2 is issued at step t; the wait before
// the consume-barrier is vmcnt(2n) (n = per-wave loads/stage), so the two
// newest stages stay in flight ACROSS the barrier (T4).  Second barrier per
// step only drains lgkmcnt (ds_reads) before the buffer is overwritten.
// Fused epilogue: q-waves LN->transpose->qn; k-waves LN->kst LDS; v-waves
// cast->vst LDS; then v-waves MFMA the 128-row partial S and atomicAdd.
// ---------------------------------------------------------------------------
__global__ __launch_bounds__(384) void k_gemm(const bf16* __restrict__ xbf,
                                              const bf16* __restrict__ Wt,
                                              const float* __restrict__ gq,
                                              const float* __restrict__ bq,
                                              const float* __restrict__ gk,
                                              const float* __restrict__ bk,
                                              bf16* __restrict__ qn,
                                              float* __restrict__ S)
{
    __shared__ union {
        struct { bf16 A[3][128 * 32]; bf16 B[3][192 * 32]; } g;            // 60 KB
        struct { bf16 q[2][64][72]; bf16 kst[64 * 128]; bf16 vst[64 * 128]; } e; // 50 KB
    } u;

    const int t    = threadIdx.x;
    const int lane = t & 63, wave = t >> 6;      // 6 waves
    const int wm   = wave & 1, ws = wave >> 1;   // row-half, section (q/k/v)
    const int orig = blockIdx.x;                 // 512 blocks, 512 % 8 == 0
    const int wg   = (orig & 7) * 64 + (orig >> 3);  // XCD-contiguous
    const int mt   = wg >> 3, h = wg & 7;
    const int m0   = mt * 128;

    const int l15 = lane & 15, l4 = lane >> 4;
    const int r4l = lane >> 2, c4 = lane & 3;    // stage: row-in-chunk, slot

    // stage one K-tile (20 x 1KB chunks: 8 A + 12 B) into LDS slot `sl`.
    // Source slot is pre-XOR-swizzled by (row&3) so LDS dest stays linear.
    // Waves 0,1 issue 4 chunks; waves 2..5 issue 3 (vmcnt counts match).
    auto stage = [&](int sl, int k0) {
        for (int c = wave; c < 20; c += 6) {
            if (c < 8) {
                const int r = c * 16 + r4l;                // tile row 0..127
                GLD16(xbf + (m0 + r) * 512 + k0 + ((c4 ^ (r & 3)) * 8),
                      u.g.A[sl] + c * 512);
            } else {
                const int rb  = (c - 8) * 16 + r4l;        // 0..191
                const int sec = rb >> 6, rin = rb & 63;    // q/k/v, row in sec
                GLD16(Wt + ((sec * 512 + h * 64 + rin) * 512 + k0 + ((c4 ^ (rb & 3)) * 8)),
                      u.g.B[sl] + (c - 8) * 512);
            }
        }
    };

    f32x4 acc[4][4] = {};

    auto compute = [&](int sl) {
        bf16x8 af[4], bfv[4];
        #pragma unroll
        for (int mf = 0; mf < 4; ++mf) {
            const int row = wm * 64 + mf * 16 + l15;
            af[mf] = *(const bf16x8*)(u.g.A[sl] + row * 32 + ((l4 ^ (row & 3)) * 8));
        }
        #pragma unroll
        for (int nf = 0; nf < 4; ++nf) {
            const int row = ws * 64 + nf * 16 + l15;       // 0..191
            bfv[nf] = *(const bf16x8*)(u.g.B[sl] + row * 32 + ((l4 ^ (row & 3)) * 8));
        }
        #pragma unroll
        for (int mf = 0; mf < 4; ++mf)
            #pragma unroll
            for (int nf = 0; nf < 4; ++nf)
                acc[mf][nf] = __builtin_amdgcn_mfma_f32_16x16x32_bf16(
                    af[mf], bfv[nf], acc[mf][nf], 0, 0, 0);
    };

    stage(0, 0);
    stage(1, 32);

#define GEMM_STEP(T, WA, WB_)                                                  \
    {                                                                          \
        if ((T) < 14) stage(((T) + 2) % 3, ((T) + 2) * 32);                    \
        if (wave < 2) { WAITVM(WA); } else { WAITVM(WB_); }                    \
        __builtin_amdgcn_sched_barrier(0);                                     \
        __builtin_amdgcn_s_barrier();          /* stage T complete for all */  \
        compute((T) % 3);                                                      \
        WAITLGKM0;                             /* ds_reads drained */          \
        __builtin_amdgcn_sched_barrier(0);                                     \
        __builtin_amdgcn_s_barrier();          /* safe to overwrite buf */     \
    }

    GEMM_STEP(0, 8, 6);  GEMM_STEP(1, 8, 6);  GEMM_STEP(2, 8, 6);
    GEMM_STEP(3, 8, 6);  GEMM_STEP(4, 8, 6);  GEMM_STEP(5, 8, 6);
    GEMM_STEP(6, 8, 6);  GEMM_STEP(7, 8, 6);  GEMM_STEP(8, 8, 6);
    GEMM_STEP(9, 8, 6);  GEMM_STEP(10, 8, 6); GEMM_STEP(11, 8, 6);
    GEMM_STEP(12, 8, 6); GEMM_STEP(13, 8, 6);
    GEMM_STEP(14, 4, 3);
    GEMM_STEP(15, 0, 0);
#undef GEMM_STEP

    // ---------------- fused epilogue (aliases g; last barrier protects) ----
    const int b  = m0 >> 11;
    const int bh = b * 8 + h;
    const int nwbase = (m0 & 2047) + wm * 64;    // seq offset of wave's 64 rows

    if (ws < 2) {
        // LayerNorm over d=64 (4 nf frags x 16 l15 lanes), stats from fp32 acc
        const float* gp = (ws == 0 ? gq : gk) + h * 64;
        const float* bp = (ws == 0 ? bq : bk) + h * 64;
        float gv[4], bv[4];
        #pragma unroll
        for (int nf = 0; nf < 4; ++nf) {
            gv[nf] = gp[nf * 16 + l15];
            bv[nf] = bp[nf * 16 + l15];
        }
        #pragma unroll
        for (int mf = 0; mf < 4; ++mf) {
            float mu[4], rs[4];
            #pragma unroll
            for (int r = 0; r < 4; ++r) {
                float s = 0.f, s2 = 0.f;
                #pragma unroll
                for (int nf = 0; nf < 4; ++nf) {
                    const float xv = acc[mf][nf][r];
                    s += xv; s2 += xv * xv;
                }
                s  += __shfl_xor(s, 1);  s  += __shfl_xor(s, 2);
                s  += __shfl_xor(s, 4);  s  += __shfl_xor(s, 8);
                s2 += __shfl_xor(s2, 1); s2 += __shfl_xor(s2, 2);
                s2 += __shfl_xor(s2, 4); s2 += __shfl_xor(s2, 8);
                mu[r] = s * (1.f / 64.f);
                rs[r] = rsqrtf(s2 * (1.f / 64.f) - mu[r] * mu[r] + 1e-5f);
            }
            #pragma unroll
            for (int nf = 0; nf < 4; ++nf) {
                bf16x4 pk;
                #pragma unroll
                for (int r = 0; r < 4; ++r)
                    pk[r] = (bf16)((acc[mf][nf][r] - mu[r]) * rs[r] * gv[nf] + bv[nf]);
                if (ws == 0) {
                    *(bf16x4*)(&u.e.q[wm][nf * 16 + l15][mf * 16 + l4 * 4]) = pk;
                } else {
                    const int d = nf * 16 + l15;
                    const int c = wm * 8 + mf * 2 + (l4 >> 1);   // n-chunk 0..15
                    *(bf16x4*)(u.e.kst + d * 128 + ((c ^ (d & 7)) * 8) + (l4 & 1) * 4) = pk;
                }
            }
        }
    } else {
        // v: plain cast into vst[d'][128n], same swizzle
        #pragma unroll
        for (int mf = 0; mf < 4; ++mf)
            #pragma unroll
            for (int nf = 0; nf < 4; ++nf) {
                bf16x4 pk;
                #pragma unroll
                for (int r = 0; r < 4; ++r) pk[r] = (bf16)acc[mf][nf][r];
                const int d = nf * 16 + l15;
                const int c = wm * 8 + mf * 2 + (l4 >> 1);
                *(bf16x4*)(u.e.vst + d * 128 + ((c ^ (d & 7)) * 8) + (l4 & 1) * 4) = pk;
            }
    }

    if (ws == 0) {
        // wave-local 4x4 transpose qep[d][n] -> qn[bh][n][d]
        bf16* dst = qn + ((long)bh * SEQ + nwbase) * 64;
        const int nq = lane & 15, dq2 = lane >> 4;
        #pragma unroll
        for (int j = 0; j < 4; ++j) {
            const int d0 = (j * 4 + dq2) * 4;
            bf16x4 a0 = *(const bf16x4*)(&u.e.q[wm][d0 + 0][nq * 4]);
            bf16x4 a1 = *(const bf16x4*)(&u.e.q[wm][d0 + 1][nq * 4]);
            bf16x4 a2 = *(const bf16x4*)(&u.e.q[wm][d0 + 2][nq * 4]);
            bf16x4 a3 = *(const bf16x4*)(&u.e.q[wm][d0 + 3][nq * 4]);
            #pragma unroll
            for (int c = 0; c < 4; ++c) {
                bf16x4 o = { a0[c], a1[c], a2[c], a3[c] };
                *(bf16x4*)(dst + (nq * 4 + c) * 64 + d0) = o;
            }
        }
    }

    __syncthreads();   // kst/vst complete for all waves

    if (ws == 2) {
        // partial S[d'][d] over this block's 128 rows; wave wm does ks pair
        f32x4 sac[4][4] = {};
        #pragma unroll
        for (int kk = 0; kk < 2; ++kk) {
            const int ksi = wm * 2 + kk;          // 0..3 (n-chunk of 32)
            const int c   = ksi * 4 + l4;         // 16B chunk 0..15
            bf16x8 av[4], bk8[4];
            #pragma unroll
            for (int i = 0; i < 4; ++i) {
                const int dp = i * 16 + l15;
                av[i] = *(const bf16x8*)(u.e.vst + dp * 128 + ((c ^ (dp & 7)) * 8));
            }
            #pragma unroll
            for (int j = 0; j < 4; ++j) {
                const int dd = j * 16 + l15;
                bk8[j] = *(const bf16x8*)(u.e.kst + dd * 128 + ((c ^ (dd & 7)) * 8));
            }
            #pragma unroll
            for (int i = 0; i < 4; ++i)
                #pragma unroll
                for (int j = 0; j < 4; ++j)
                    sac[i][j] = __builtin_amdgcn_mfma_f32_16x16x32_bf16(
                        av[i], bk8[j], sac[i][j], 0, 0, 0);
        }
        float* Sb = S + bh * 4096;
        #pragma unroll
        for (int i = 0; i < 4; ++i)
            #pragma unroll
            for (int j = 0; j < 4; ++j)
                #pragma unroll
                for (int r = 0; r < 4; ++r) {
                    const int dp = i * 16 + l4 * 4 + r;   // d'
                    const int dd = j * 16 + l15;          // d
                    atomicAdd(Sb + dp * 64 + dd, sac[i][j][r]);
                }
    }
}

// ---------------------------------------------------------------------------
// Kernel 3: out[b][n][h*64+d'] = sum_d qn[bh][n][d] * (S[bh][d'][d] * 2^-14)
// 512 blocks x 4 waves; each wave owns 32 seq rows (2048 waves -> 8/CU).
// Scale folded into the S->bf16 conversion (exact power of two).
// ---------------------------------------------------------------------------
__global__ __launch_bounds__(256) void k_out(const bf16* __restrict__ qn,
                                             const float* __restrict__ S,
                                             float* __restrict__ out)
{
    const int bid = blockIdx.x;
    const int bh = bid >> 4, nt4 = bid & 15;
    const int b = bh >> 3, h = bh & 7;
    const int t = threadIdx.x, lane = t & 63, wave = t >> 6;
    const int l15 = lane & 15, l4 = lane >> 4;
    const float* Sb = S + bh * 4096;
    const float scale = 1.f / 16384.f;   // (64^-0.5)/2048 exactly

    bf16x8 bfr[2][4];
    #pragma unroll
    for (int kh = 0; kh < 2; ++kh)
        #pragma unroll
        for (int cf = 0; cf < 4; ++cf) {
            const float* p = Sb + (cf * 16 + l15) * 64 + kh * 32 + l4 * 8;
            float4 lo = *(const float4*)(p);
            float4 hi = *(const float4*)(p + 4);
            bf16x8 f;
            f[0] = (bf16)(lo.x * scale); f[1] = (bf16)(lo.y * scale);
            f[2] = (bf16)(lo.z * scale); f[3] = (bf16)(lo.w * scale);
            f[4] = (bf16)(hi.x * scale); f[5] = (bf16)(hi.y * scale);
            f[6] = (bf16)(hi.z * scale); f[7] = (bf16)(hi.w * scale);
            bfr[kh][cf] = f;
        }

    const bf16* qb = qn + (long)bh * SEQ * 64;
    const int nbase = nt4 * 128 + wave * 32;

    #pragma unroll
    for (int mf = 0; mf < 2; ++mf) {
        bf16x8 a0 = *(const bf16x8*)(qb + (nbase + mf * 16 + l15) * 64 +      l4 * 8);
        bf16x8 a1 = *(const bf16x8*)(qb + (nbase + mf * 16 + l15) * 64 + 32 + l4 * 8);
        f32x4 acc[4] = {};
        #pragma unroll
        for (int cf = 0; cf < 4; ++cf) {
            acc[cf] = __builtin_amdgcn_mfma_f32_16x16x32_bf16(a0, bfr[0][cf], acc[cf], 0, 0, 0);
            acc[cf] = __builtin_amdgcn_mfma_f32_16x16x32_bf16(a1, bfr[1][cf], acc[cf], 0, 0, 0);
        }
        #pragma unroll
        for (int cf = 0; cf < 4; ++cf)
            #pragma unroll
            for (int r = 0; r < 4; ++r) {
                const int n = nbase + mf * 16 + l4 * 4 + r;
                out[((long)b * SEQ + n) * 512 + h * 64 + cf * 16 + l15] = acc[cf][r];
            }
    }
}

// ---------------------------------------------------------------------------
extern "C" void kernel_launch(void* const* d_in, const int* in_sizes, int n_in,
                              void* d_out, int out_size, void* d_ws, size_t ws_size,
                              hipStream_t stream)
{
    const float* x  = (const float*)d_in[0];
    const float* w  = (const float*)d_in[1];
    const float* gq = (const float*)d_in[2];
    const float* bq = (const float*)d_in[3];
    const float* gk = (const float*)d_in[4];
    const float* bk = (const float*)d_in[5];
    float* out = (float*)d_out;

    char* ws = (char*)d_ws;
    // layout (bytes):
    //   xbf bf16 : 0        .. 8388608
    //   wt  bf16 : 8388608  .. 9961472
    //   qn  bf16 : 9961472  .. 18350080
    //   S   fp32 : 18350080 .. 18874368   (~18 MB total)
    bf16*  xbf = (bf16*)(ws);
    bf16*  wt  = (bf16*)(ws + 8388608);
    bf16*  qn  = (bf16*)(ws + 9961472);
    float* S   = (float*)(ws + 18350080);

    hipLaunchKernelGGL(k_prep, dim3(4096 + 768 + 128), dim3(256), 0, stream,
                       x, w, xbf, wt, S);
    hipLaunchKernelGGL(k_gemm, dim3(512), dim3(384), 0, stream,
                       xbf, wt, gq, bq, gk, bk, qn, S);
    hipLaunchKernelGGL(k_out,  dim3(512), dim3(256), 0, stream, qn, S, out);
}

// Round 6
// 119.932 us; speedup vs baseline: 1.1292x; 1.1292x over previous
//
#include <hip/hip_runtime.h>
#include <hip/hip_bf16.h>
#include <stdint.h>

using bf16   = __bf16;
using bf16x4 = __attribute__((ext_vector_type(4))) __bf16;
using bf16x8 = __attribute__((ext_vector_type(8))) __bf16;
using f32x4  = __attribute__((ext_vector_type(4))) float;

// geometry (fixed by the problem)
static constexpr int BATCH = 4, SEQ = 2048, DIM = 512, HEADS = 8, DK = 64;
static constexpr int M    = BATCH * SEQ;   // 8192 rows of x
static constexpr int NQKV = 3 * DIM;       // 1536

#define GLD16(src, dst)                                                        \
    __builtin_amdgcn_global_load_lds(                                          \
        (const __attribute__((address_space(1))) void*)(src),                  \
        (__attribute__((address_space(3))) void*)(dst), 16, 0, 0)

// ---------------------------------------------------------------------------
// Kernel 1 (tiny): W [512][1536] fp32 -> Wt [1536][512] bf16.
// ---------------------------------------------------------------------------
__global__ __launch_bounds__(256) void k_prep(const float* __restrict__ w,
                                              bf16* __restrict__ wt)
{
    const int bid = blockIdx.x;                             // 768 blocks
    const int t   = threadIdx.x;
    const int rt = bid / 48, ct = bid - rt * 48;            // k-tile, n-tile
    __shared__ float tile[32][33];
    const int r = t >> 5, c = t & 31;
    #pragma unroll
    for (int i = 0; i < 4; ++i)
        tile[r + i * 8][c] = w[(rt * 32 + r + i * 8) * NQKV + ct * 32 + c];
    __syncthreads();
    #pragma unroll
    for (int i = 0; i < 4; ++i)
        wt[(ct * 32 + r + i * 8) * DIM + rt * 32 + c] = (bf16)tile[c][r + i * 8];
}

// ---------------------------------------------------------------------------
// Kernel 2 (mega): per (m-tile 128, head h): GEMM cols {q_h|k_h|v_h}
// (128x192, 6 waves of 64x64, BK=64, single-buffered).  A is reg-staged from
// fp32 x (convert + swizzled ds_write); B via global_load_lds of Wt.
// Fused epilogue: q-waves LN->transpose->qn; k-waves LN->kst LDS; v-waves
// cast->vst LDS; barrier; v-waves MFMA the 128-row partial S[d'][d] and
// PLAIN-STORE it to Sp[mt*8+h] (no atomics; reduced later in k_out).
// ---------------------------------------------------------------------------
__global__ __launch_bounds__(384) void k_gemm(const float* __restrict__ x,
                                              const bf16* __restrict__ Wt,
                                              const float* __restrict__ gq,
                                              const float* __restrict__ bq,
                                              const float* __restrict__ gk,
                                              const float* __restrict__ bk,
                                              bf16* __restrict__ qn,
                                              float* __restrict__ Sp)
{
    __shared__ union {
        struct { bf16 A[128 * 64]; bf16 B[192 * 64]; } g;          // 40 KB
        struct { bf16 q[2][64][72]; bf16 kst[64 * 128]; bf16 vst[64 * 128]; } e; // 50 KB
    } u;

    const int t    = threadIdx.x;
    const int lane = t & 63, wave = t >> 6;      // 6 waves
    const int wm   = wave & 1, ws = wave >> 1;   // row-half, section (q/k/v)
    const int orig = blockIdx.x;                 // 512 blocks, 512 % 8 == 0
    const int wg   = (orig & 7) * 64 + (orig >> 3);  // XCD-contiguous
    const int mt   = wg >> 3, h = wg & 7;
    const int m0   = mt * 128;

    const int l15 = lane & 15, l4 = lane >> 4;
    const int rl  = lane >> 3, cl = (lane & 7) ^ rl;   // swizzled GLD src chunk

    f32x4 acc[4][4] = {};

    for (int k0 = 0; k0 < 512; k0 += 64) {
        // ---- B staging: 24 x 1KB chunks via global_load_lds (4 per wave) ----
        #pragma unroll
        for (int i = 0; i < 4; ++i) {
            const int ch  = wave * 4 + i;        // 0..23
            const int sec = ch >> 3;             // 0=q 1=k 2=v
            const int r   = (ch & 7) * 8 + rl;   // row within section (0..63)
            GLD16(Wt + ((sec * 512 + h * 64 + r) * 512 + k0 + cl * 8),
                  u.g.B + ch * 512);
        }
        // ---- A staging: fp32 x -> bf16, swizzled ds_write ----
        for (int i = t; i < 2048; i += 384) {
            const int row = i >> 4, ch = i & 15;           // 16B fp32 chunks
            float4 v = *(const float4*)(x + (m0 + row) * 512 + k0 + ch * 4);
            bf16x4 o = { (bf16)v.x, (bf16)v.y, (bf16)v.z, (bf16)v.w };
            *(bf16x4*)(u.g.A + row * 64 + (((ch >> 1) ^ (row & 7)) * 8) + (ch & 1) * 4) = o;
        }
        __syncthreads();
        // ---- MFMA ----
        #pragma unroll
        for (int kh = 0; kh < 2; ++kh) {
            bf16x8 af[4], bfv[4];
            const int rc = kh * 4 + l4;
            #pragma unroll
            for (int mf = 0; mf < 4; ++mf) {
                const int row = wm * 64 + mf * 16 + l15;
                af[mf] = *(const bf16x8*)(u.g.A + row * 64 + ((rc ^ (row & 7)) * 8));
            }
            #pragma unroll
            for (int nf = 0; nf < 4; ++nf) {
                const int row = ws * 64 + nf * 16 + l15;   // 0..191
                bfv[nf] = *(const bf16x8*)(u.g.B + row * 64 + ((rc ^ (row & 7)) * 8));
            }
            #pragma unroll
            for (int mf = 0; mf < 4; ++mf)
                #pragma unroll
                for (int nf = 0; nf < 4; ++nf)
                    acc[mf][nf] = __builtin_amdgcn_mfma_f32_16x16x32_bf16(
                        af[mf], bfv[nf], acc[mf][nf], 0, 0, 0);
        }
        __syncthreads();
    }

    // ---------------- fused epilogue ----------------
    const int b  = m0 >> 11;
    const int bh = b * 8 + h;
    const int nwbase = (m0 & 2047) + wm * 64;    // seq offset of wave's 64 rows

    if (ws < 2) {
        // LayerNorm over d=64 (4 nf frags x 16 l15 lanes), stats from fp32 acc
        const float* gp = (ws == 0 ? gq : gk) + h * 64;
        const float* bp = (ws == 0 ? bq : bk) + h * 64;
        float gv[4], bv[4];
        #pragma unroll
        for (int nf = 0; nf < 4; ++nf) {
            gv[nf] = gp[nf * 16 + l15];
            bv[nf] = bp[nf * 16 + l15];
        }
        #pragma unroll
        for (int mf = 0; mf < 4; ++mf) {
            float mu[4], rs[4];
            #pragma unroll
            for (int r = 0; r < 4; ++r) {
                float s = 0.f, s2 = 0.f;
                #pragma unroll
                for (int nf = 0; nf < 4; ++nf) {
                    const float xv = acc[mf][nf][r];
                    s += xv; s2 += xv * xv;
                }
                s  += __shfl_xor(s, 1);  s  += __shfl_xor(s, 2);
                s  += __shfl_xor(s, 4);  s  += __shfl_xor(s, 8);
                s2 += __shfl_xor(s2, 1); s2 += __shfl_xor(s2, 2);
                s2 += __shfl_xor(s2, 4); s2 += __shfl_xor(s2, 8);
                mu[r] = s * (1.f / 64.f);
                rs[r] = rsqrtf(s2 * (1.f / 64.f) - mu[r] * mu[r] + 1e-5f);
            }
            #pragma unroll
            for (int nf = 0; nf < 4; ++nf) {
                bf16x4 pk;
                #pragma unroll
                for (int r = 0; r < 4; ++r)
                    pk[r] = (bf16)((acc[mf][nf][r] - mu[r]) * rs[r] * gv[nf] + bv[nf]);
                if (ws == 0) {
                    *(bf16x4*)(&u.e.q[wm][nf * 16 + l15][mf * 16 + l4 * 4]) = pk;
                } else {
                    const int d = nf * 16 + l15;
                    const int c = wm * 8 + mf * 2 + (l4 >> 1);   // n-chunk 0..15
                    *(bf16x4*)(u.e.kst + d * 128 + ((c ^ (d & 7)) * 8) + (l4 & 1) * 4) = pk;
                }
            }
        }
    } else {
        // v: plain cast into vst[d'][128n], same swizzle
        #pragma unroll
        for (int mf = 0; mf < 4; ++mf)
            #pragma unroll
            for (int nf = 0; nf < 4; ++nf) {
                bf16x4 pk;
                #pragma unroll
                for (int r = 0; r < 4; ++r) pk[r] = (bf16)acc[mf][nf][r];
                const int d = nf * 16 + l15;
                const int c = wm * 8 + mf * 2 + (l4 >> 1);
                *(bf16x4*)(u.e.vst + d * 128 + ((c ^ (d & 7)) * 8) + (l4 & 1) * 4) = pk;
            }
    }

    if (ws == 0) {
        // wave-local 4x4 transpose qep[d][n] -> qn[bh][n][d]
        bf16* dst = qn + ((long)bh * SEQ + nwbase) * 64;
        const int nq = lane & 15, dq2 = lane >> 4;
        #pragma unroll
        for (int j = 0; j < 4; ++j) {
            const int d0 = (j * 4 + dq2) * 4;
            bf16x4 a0 = *(const bf16x4*)(&u.e.q[wm][d0 + 0][nq * 4]);
            bf16x4 a1 = *(const bf16x4*)(&u.e.q[wm][d0 + 1][nq * 4]);
            bf16x4 a2 = *(const bf16x4*)(&u.e.q[wm][d0 + 2][nq * 4]);
            bf16x4 a3 = *(const bf16x4*)(&u.e.q[wm][d0 + 3][nq * 4]);
            #pragma unroll
            for (int c = 0; c < 4; ++c) {
                bf16x4 o = { a0[c], a1[c], a2[c], a3[c] };
                *(bf16x4*)(dst + (nq * 4 + c) * 64 + d0) = o;
            }
        }
    }

    __syncthreads();   // kst/vst complete for all waves

    if (ws == 2) {
        // partial S[d'][d] over this block's 128 rows; wave wm does ks pair
        f32x4 sac[4][4] = {};
        #pragma unroll
        for (int kk = 0; kk < 2; ++kk) {
            const int ksi = wm * 2 + kk;          // 0..3 (n-chunk of 32)
            const int c   = ksi * 4 + l4;         // 16B chunk 0..15
            bf16x8 av[4], bk8[4];
            #pragma unroll
            for (int i = 0; i < 4; ++i) {
                const int dp = i * 16 + l15;
                av[i] = *(const bf16x8*)(u.e.vst + dp * 128 + ((c ^ (dp & 7)) * 8));
            }
            #pragma unroll
            for (int j = 0; j < 4; ++j) {
                const int dd = j * 16 + l15;
                bk8[j] = *(const bf16x8*)(u.e.kst + dd * 128 + ((c ^ (dd & 7)) * 8));
            }
            #pragma unroll
            for (int i = 0; i < 4; ++i)
                #pragma unroll
                for (int j = 0; j < 4; ++j)
                    sac[i][j] = __builtin_amdgcn_mfma_f32_16x16x32_bf16(
                        av[i], bk8[j], sac[i][j], 0, 0, 0);
        }
        // the two ws==2 waves hold DISJOINT n-chunks -> must sum across wm.
        // Use LDS staging: wm=0 writes its tile, barrier, wm=1 adds + stores.
        float* red = (float*)u.e.q;               // 16KB scratch (q area free)
        if (wm == 0) {
            #pragma unroll
            for (int i = 0; i < 4; ++i)
                #pragma unroll
                for (int j = 0; j < 4; ++j)
                    *(f32x4*)(red + ((i * 16 + l4 * 4) * 64 + j * 16 + l15) + 0) =
                        (f32x4){0.f, 0.f, 0.f, 0.f};  // placeholder; real write below
        }
        // NOTE: acc lanes hold dp rows in [r]; store per element.
        if (wm == 0) {
            #pragma unroll
            for (int i = 0; i < 4; ++i)
                #pragma unroll
                for (int j = 0; j < 4; ++j)
                    #pragma unroll
                    for (int r = 0; r < 4; ++r)
                        red[(i * 16 + l4 * 4 + r) * 64 + j * 16 + l15] = sac[i][j][r];
        }
        __builtin_amdgcn_s_barrier();
        if (wm == 1) {
            float* Sb = Sp + (long)(mt * 8 + h) * 4096;
            #pragma unroll
            for (int i = 0; i < 4; ++i)
                #pragma unroll
                for (int j = 0; j < 4; ++j)
                    #pragma unroll
                    for (int r = 0; r < 4; ++r) {
                        const int dp = i * 16 + l4 * 4 + r;
                        const int dd = j * 16 + l15;
                        Sb[dp * 64 + dd] = sac[i][j][r] + red[dp * 64 + dd];
                    }
        }
    }
}

// ---------------------------------------------------------------------------
// Kernel 3: reduce Sp over the batch's 16 m-tiles, then
// out[b][n][h*64+d'] = sum_d qn[bh][n][d] * (S[bh][d'][d] * 2^-14)
// 256 blocks (32 bh x 8 n-tiles of 256), 4 waves x 64 rows.
// ---------------------------------------------------------------------------
__global__ __launch_bounds__(256) void k_out(const bf16* __restrict__ qn,
                                             const float* __restrict__ Sp,
                                             float* __restrict__ out)
{
    __shared__ float sS[64 * 68];                // padded [64][68]
    const int bid = blockIdx.x;
    const int bh = bid >> 3, nt8 = bid & 7;
    const int b = bh >> 3, h = bh & 7;
    const int t = threadIdx.x, lane = t & 63, wave = t >> 6;
    const int l15 = lane & 15, l4 = lane >> 4;

    // ---- reduce 16 partials (coalesced: inst j covers 1KB across lanes) ----
    f32x4 racc[4] = {};
    for (int mt16 = 0; mt16 < 16; ++mt16) {
        const float* p = Sp + (long)(((b * 16 + mt16) * 8) + h) * 4096 + t * 4;
        #pragma unroll
        for (int j = 0; j < 4; ++j)
            racc[j] += *(const f32x4*)(p + j * 1024);
    }
    #pragma unroll
    for (int j = 0; j < 4; ++j) {
        const int f  = j * 1024 + t * 4;
        const int dp = f >> 6, dd = f & 63;
        *(f32x4*)(sS + dp * 68 + dd) = racc[j];
    }
    __syncthreads();

    // ---- build bf16 B-frags with scale folded in ----
    const float scale = 1.f / 16384.f;           // (64^-0.5)/2048 exactly
    bf16x8 bfr[2][4];
    #pragma unroll
    for (int kh = 0; kh < 2; ++kh)
        #pragma unroll
        for (int cf = 0; cf < 4; ++cf) {
            const float* p = sS + (cf * 16 + l15) * 68 + kh * 32 + l4 * 8;
            float4 lo = *(const float4*)(p);
            float4 hi = *(const float4*)(p + 4);
            bf16x8 f;
            f[0] = (bf16)(lo.x * scale); f[1] = (bf16)(lo.y * scale);
            f[2] = (bf16)(lo.z * scale); f[3] = (bf16)(lo.w * scale);
            f[4] = (bf16)(hi.x * scale); f[5] = (bf16)(hi.y * scale);
            f[6] = (bf16)(hi.z * scale); f[7] = (bf16)(hi.w * scale);
            bfr[kh][cf] = f;
        }

    const bf16* qb = qn + (long)bh * SEQ * 64;
    const int nbase = nt8 * 256 + wave * 64;

    #pragma unroll
    for (int mf = 0; mf < 4; ++mf) {
        bf16x8 a0 = *(const bf16x8*)(qb + (nbase + mf * 16 + l15) * 64 +      l4 * 8);
        bf16x8 a1 = *(const bf16x8*)(qb + (nbase + mf * 16 + l15) * 64 + 32 + l4 * 8);
        f32x4 acc[4] = {};
        #pragma unroll
        for (int cf = 0; cf < 4; ++cf) {
            acc[cf] = __builtin_amdgcn_mfma_f32_16x16x32_bf16(a0, bfr[0][cf], acc[cf], 0, 0, 0);
            acc[cf] = __builtin_amdgcn_mfma_f32_16x16x32_bf16(a1, bfr[1][cf], acc[cf], 0, 0, 0);
        }
        #pragma unroll
        for (int cf = 0; cf < 4; ++cf)
            #pragma unroll
            for (int r = 0; r < 4; ++r) {
                const int n = nbase + mf * 16 + l4 * 4 + r;
                out[((long)b * SEQ + n) * 512 + h * 64 + cf * 16 + l15] = acc[cf][r];
            }
    }
}

// ---------------------------------------------------------------------------
extern "C" void kernel_launch(void* const* d_in, const int* in_sizes, int n_in,
                              void* d_out, int out_size, void* d_ws, size_t ws_size,
                              hipStream_t stream)
{
    const float* x  = (const float*)d_in[0];
    const float* w  = (const float*)d_in[1];
    const float* gq = (const float*)d_in[2];
    const float* bq = (const float*)d_in[3];
    const float* gk = (const float*)d_in[4];
    const float* bk = (const float*)d_in[5];
    float* out = (float*)d_out;

    char* ws = (char*)d_ws;
    // layout (bytes):
    //   wt  bf16 : 0        .. 1572864
    //   qn  bf16 : 1572864  .. 9961472
    //   Sp  fp32 : 9961472  .. 18350080  (64 mt x 8 h x 4096 f32 = 8 MB)
    bf16*  wt = (bf16*)(ws);
    bf16*  qn = (bf16*)(ws + 1572864);
    float* Sp = (float*)(ws + 9961472);

    hipLaunchKernelGGL(k_prep, dim3(768), dim3(256), 0, stream, w, wt);
    hipLaunchKernelGGL(k_gemm, dim3(512), dim3(384), 0, stream,
                       x, wt, gq, bq, gk, bk, qn, Sp);
    hipLaunchKernelGGL(k_out,  dim3(256), dim3(256), 0, stream, qn, Sp, out);
}